// Round 8
// baseline (352.437 us; speedup 1.0000x reference)
//
#include <hip/hip_runtime.h>
#include <hip/hip_bf16.h>

#define B_SZ   1024
#define HIDN   256
#define NSTAGE 6
#define NPTS   36
#define HGT    20
#define WID    20
#define HW     400
#define MB     4
#define NTHR   1024

// f32 -> bf16 round-to-nearest-even
static __device__ __forceinline__ unsigned int f2bf(float x) {
    unsigned int u = __float_as_uint(x);
    u += 0x7FFFu + ((u >> 16) & 1u);
    return u >> 16;
}
// bf16 bits -> f32 (exact)
static __device__ __forceinline__ float bf2f(unsigned short h) {
    return __uint_as_float((unsigned int)h << 16);
}

// ---------------------------------------------------------------------------
// Prepass v7: fmp layout [b][ct][hw][cw]  (ct = c/64, cw = c%64).
//   element index = ((b*4 + ct)*400 + hw)*64 + cw
// Block (ct, b): reads fm/pos rows c = ct*64..+63 -> TWO fully contiguous
// 102.4 KB streams; writes ONE fully contiguous 51.2 KB stream.
// LDS transpose tile[hw][cw], ushort stride 65 (odd):
//   - read phase: 4x ds_write_b16 at word-stride 130 (mod 32 = 2) -> 2-way, free
//   - write phase: ushort reads, lanes u2=0..31 at byte 130*hw+4*u2 -> 32 banks, free
// 512 threads, 52 KB LDS -> 3 blocks/CU.
// ---------------------------------------------------------------------------
__global__ __launch_bounds__(512) void prepass_kernel(
    const float* __restrict__ fm, const float* __restrict__ pos,
    unsigned short* __restrict__ fmp)
{
    const int b  = blockIdx.y;
    const int ct = blockIdx.x;                    // 0..3
    __shared__ unsigned short tile[HW * 65];      // 52,000 B
    const int t = threadIdx.x;

    // ---- read + convert: 64 rows x 400 f32 = 6400 float4 per array, flat ----
    const size_t gbase = ((size_t)b * HIDN + ct * 64) * HW;
    for (int i = t; i < 6400; i += 512) {
        const int c  = i / 100;                   // local channel 0..63
        const int k4 = i - c * 100;               // float4 along hw 0..99
        const float4 a = *(const float4*)(fm  + gbase + 4 * (size_t)i);
        const float4 p = *(const float4*)(pos + gbase + 4 * (size_t)i);
        tile[(4 * k4 + 0) * 65 + c] = (unsigned short)f2bf(a.x + p.x);
        tile[(4 * k4 + 1) * 65 + c] = (unsigned short)f2bf(a.y + p.y);
        tile[(4 * k4 + 2) * 65 + c] = (unsigned short)f2bf(a.z + p.z);
        tile[(4 * k4 + 3) * 65 + c] = (unsigned short)f2bf(a.w + p.w);
    }
    __syncthreads();

    // ---- contiguous write: 400 rows x 128 B sequential ----
    const int u2 = t & 31;                        // channel pair 0..31
    const int h0 = t >> 5;                        // 0..15
    uint* outp = (uint*)(fmp + (((size_t)b * 4 + ct) * HW) * 64);
    for (int hw = h0; hw < HW; hw += 16) {
        const unsigned int lo = tile[hw * 65 + 2 * u2 + 0];
        const unsigned int hi = tile[hw * 65 + 2 * u2 + 1];
        outp[(size_t)hw * 32 + u2] = lo | (hi << 16);
    }
}

// ---------------------------------------------------------------------------
// GEMM for 4 batch elements, no arrays (anti-spill), kp-split coalesced W.
// Thread layout: kp = t&7, og = t>>3 (0..127). O<=128 per pass.
// ACT: 0=none, 1=relu, 2=sigmoid.
// ---------------------------------------------------------------------------
template <int K, int O, int ACT>
__device__ __forceinline__ void gemm_v3(
    const float* __restrict__ W, const float* __restrict__ bias,
    const float* __restrict__ i0, const float* __restrict__ i1,
    const float* __restrict__ i2, const float* __restrict__ i3,
    float* __restrict__ o0, float* __restrict__ o1,
    float* __restrict__ o2, float* __restrict__ o3,
    int kp, int og)
{
    const float4* p0 = (const float4*)i0;
    const float4* p1 = (const float4*)i1;
    const float4* p2 = (const float4*)i2;
    const float4* p3 = (const float4*)i3;
    #pragma unroll
    for (int pass = 0; pass < (O + 127) / 128; ++pass) {
        const int o = pass * 128 + og;
        float a0 = 0.f, a1 = 0.f, a2 = 0.f, a3 = 0.f;
        if (o < O) {
            const float4* wr = (const float4*)(W + (size_t)o * K);
            #pragma unroll 4
            for (int jj = 0; jj < K / 32; ++jj) {
                const int j = kp + 8 * jj;
                const float4 w  = wr[j];
                const float4 v0 = p0[j];
                const float4 v1 = p1[j];
                const float4 v2 = p2[j];
                const float4 v3 = p3[j];
                a0 += w.x * v0.x + w.y * v0.y + w.z * v0.z + w.w * v0.w;
                a1 += w.x * v1.x + w.y * v1.y + w.z * v1.z + w.w * v1.w;
                a2 += w.x * v2.x + w.y * v2.y + w.z * v2.z + w.w * v2.w;
                a3 += w.x * v3.x + w.y * v3.y + w.z * v3.z + w.w * v3.w;
            }
        }
        a0 += __shfl_xor(a0, 1); a0 += __shfl_xor(a0, 2); a0 += __shfl_xor(a0, 4);
        a1 += __shfl_xor(a1, 1); a1 += __shfl_xor(a1, 2); a1 += __shfl_xor(a1, 4);
        a2 += __shfl_xor(a2, 1); a2 += __shfl_xor(a2, 2); a2 += __shfl_xor(a2, 4);
        a3 += __shfl_xor(a3, 1); a3 += __shfl_xor(a3, 2); a3 += __shfl_xor(a3, 4);
        if (kp == 0 && o < O) {
            const float bz = bias[o];
            float r0 = a0 + bz, r1 = a1 + bz, r2 = a2 + bz, r3 = a3 + bz;
            if (ACT == 1) {
                r0 = fmaxf(r0, 0.f); r1 = fmaxf(r1, 0.f);
                r2 = fmaxf(r2, 0.f); r3 = fmaxf(r3, 0.f);
            }
            if (ACT == 2) {
                r0 = 1.f / (1.f + expf(-r0)); r1 = 1.f / (1.f + expf(-r1));
                r2 = 1.f / (1.f + expf(-r2)); r3 = 1.f / (1.f + expf(-r3));
            }
            o0[o] = r0; o1[o] = r1; o2[o] = r2; o3[o] = r3;
        }
    }
}

// ---------------------------------------------------------------------------
// Fused main kernel v5: 1 block = 4 batch elements, 1024 threads, 256 blocks.
// Gathers from bf16 fmp in [b][ct][hw][cw] layout: per wave (one ct) each
// tap is a 128B contiguous read, same as before; only address math changed.
// ---------------------------------------------------------------------------
__global__ __launch_bounds__(NTHR) void mdetr5_kernel(
    const float* __restrict__ q_in,  const float* __restrict__ refpt,
    const unsigned short* __restrict__ fmp,
    const float* __restrict__ offW,  const float* __restrict__ offB,
    const float* __restrict__ uW1,   const float* __restrict__ uB1,
    const float* __restrict__ uW2,   const float* __restrict__ uB2,
    const float* __restrict__ bW1,   const float* __restrict__ bb1,
    const float* __restrict__ bW2,   const float* __restrict__ bb2,
    const float* __restrict__ bW3,   const float* __restrict__ bb3,
    float* __restrict__ out)
{
    const int b0 = blockIdx.x * MB;
    const int t  = threadIdx.x;
    const int kp = t & 7;
    const int og = t >> 3;

    __shared__ __attribute__((aligned(16))) float cat_s[MB][2 * HIDN]; // [fused|q]
    __shared__ __attribute__((aligned(16))) float hdd_s[MB][HIDN];
    __shared__ __attribute__((aligned(16))) float xy_s[MB][80];
    __shared__ __attribute__((aligned(16))) float wgt_s[MB][144];
    __shared__ __attribute__((aligned(16))) int   off_s[MB][144];

    {   // initial q
        const int m = t >> 8, c = t & 255;
        cat_s[m][HIDN + c] = q_in[(size_t)(b0 + m) * HIDN + c];
    }

    for (int s = 0; s < NSTAGE; ++s) {
        __syncthreads();
        // ---- offset generator ----
        gemm_v3<HIDN, NPTS * 2, 0>(
            offW + (size_t)s * NPTS * 2 * HIDN, offB + s * NPTS * 2,
            cat_s[0] + HIDN, cat_s[1] + HIDN, cat_s[2] + HIDN, cat_s[3] + HIDN,
            xy_s[0], xy_s[1], xy_s[2], xy_s[3], kp, og);
        __syncthreads();
        // ---- tap prep (offsets scaled for 64-channel sub-rows) ----
        if (t < MB * NPTS) {
            const int m = t / NPTS, p = t % NPTS;
            const int bm = b0 + m;
            float px = xy_s[m][2 * p + 0] + refpt[2 * bm + 0];
            float py = xy_s[m][2 * p + 1] + refpt[2 * bm + 1];
            float x = fminf(fmaxf(px * (float)WID - 0.5f, 0.f), (float)(WID - 1));
            float y = fminf(fmaxf(py * (float)HGT - 0.5f, 0.f), (float)(HGT - 1));
            float x0f = floorf(x), y0f = floorf(y);
            float wx = x - x0f,   wy = y - y0f;
            int x0 = (int)x0f, y0 = (int)y0f;
            int x1 = min(x0 + 1, WID - 1), y1 = min(y0 + 1, HGT - 1);
            const float inv = 1.f / (float)NPTS;
            wgt_s[m][4 * p + 0] = (1.f - wx) * (1.f - wy) * inv;
            wgt_s[m][4 * p + 1] = wx * (1.f - wy) * inv;
            wgt_s[m][4 * p + 2] = (1.f - wx) * wy * inv;
            wgt_s[m][4 * p + 3] = wx * wy * inv;
            off_s[m][4 * p + 0] = (y0 * WID + x0) * 64;
            off_s[m][4 * p + 1] = (y0 * WID + x1) * 64;
            off_s[m][4 * p + 2] = (y1 * WID + x0) * 64;
            off_s[m][4 * p + 3] = (y1 * WID + x1) * 64;
        }
        __syncthreads();
        // ---- gather + pooled mean -> fused ----
        {
            const int m = t >> 8, c = t & 255;
            const unsigned short* base =
                fmp + (((size_t)(b0 + m) * 4 + (c >> 6)) * HW) * 64 + (c & 63);
            float acc = 0.f;
            #pragma unroll 6
            for (int p = 0; p < NPTS; ++p) {
                const int4   o4 = ((const int4*)off_s[m])[p];
                const float4 w4 = ((const float4*)wgt_s[m])[p];
                acc += w4.x * bf2f(base[o4.x]) + w4.y * bf2f(base[o4.y])
                     + w4.z * bf2f(base[o4.z]) + w4.w * bf2f(base[o4.w]);
            }
            cat_s[m][c] = acc;
        }
        __syncthreads();
        // ---- MLP1 ----
        gemm_v3<2 * HIDN, HIDN, 1>(
            uW1 + (size_t)s * HIDN * 2 * HIDN, uB1 + s * HIDN,
            cat_s[0], cat_s[1], cat_s[2], cat_s[3],
            hdd_s[0], hdd_s[1], hdd_s[2], hdd_s[3], kp, og);
        __syncthreads();
        // ---- MLP2 ----
        gemm_v3<HIDN, HIDN, 0>(
            uW2 + (size_t)s * HIDN * HIDN, uB2 + s * HIDN,
            hdd_s[0], hdd_s[1], hdd_s[2], hdd_s[3],
            cat_s[0] + HIDN, cat_s[1] + HIDN, cat_s[2] + HIDN, cat_s[3] + HIDN,
            kp, og);
    }
    __syncthreads();
    // ---- bbox head ----
    gemm_v3<HIDN, HIDN, 1>(bW1, bb1,
        cat_s[0] + HIDN, cat_s[1] + HIDN, cat_s[2] + HIDN, cat_s[3] + HIDN,
        hdd_s[0], hdd_s[1], hdd_s[2], hdd_s[3], kp, og);
    __syncthreads();
    gemm_v3<HIDN, HIDN, 1>(bW2, bb2,
        hdd_s[0], hdd_s[1], hdd_s[2], hdd_s[3],
        cat_s[0], cat_s[1], cat_s[2], cat_s[3], kp, og);
    __syncthreads();
    gemm_v3<HIDN, 4, 2>(bW3, bb3,
        cat_s[0], cat_s[1], cat_s[2], cat_s[3],
        out + (size_t)(b0 + 0) * 4, out + (size_t)(b0 + 1) * 4,
        out + (size_t)(b0 + 2) * 4, out + (size_t)(b0 + 3) * 4, kp, og);
}

// ---------------------------------------------------------------------------
// Fallback (no workspace): 1 block = 1 batch element, direct strided gather.
// ---------------------------------------------------------------------------
__global__ __launch_bounds__(256) void mdetr_direct_kernel(
    const float* __restrict__ q_in,  const float* __restrict__ refpt,
    const float* __restrict__ fm,    const float* __restrict__ pos,
    const float* __restrict__ offW,  const float* __restrict__ offB,
    const float* __restrict__ uW1,   const float* __restrict__ uB1,
    const float* __restrict__ uW2,   const float* __restrict__ uB2,
    const float* __restrict__ bW1,   const float* __restrict__ bb1,
    const float* __restrict__ bW2,   const float* __restrict__ bb2,
    const float* __restrict__ bW3,   const float* __restrict__ bb3,
    float* __restrict__ out)
{
    const int b = blockIdx.x;
    const int t = threadIdx.x;
    __shared__ __attribute__((aligned(16))) float q_s[HIDN];
    __shared__ __attribute__((aligned(16))) float fused_s[HIDN];
    __shared__ __attribute__((aligned(16))) float hdd_s[HIDN];
    __shared__ float xy_s[NPTS * 2];
    __shared__ int   off_s[NPTS * 4];
    __shared__ float w_s[NPTS * 4];

    q_s[t] = q_in[(size_t)b * HIDN + t];
    const float rpx = refpt[2 * b + 0];
    const float rpy = refpt[2 * b + 1];

    for (int s = 0; s < NSTAGE; ++s) {
        __syncthreads();
        if (t < NPTS * 2) {
            const float4* wrow = (const float4*)(offW + ((size_t)s * 72 + t) * HIDN);
            const float4* q4   = (const float4*)q_s;
            float a0 = 0.f;
            #pragma unroll 8
            for (int k = 0; k < HIDN / 4; ++k) {
                float4 w4 = wrow[k]; float4 qq = q4[k];
                a0 += w4.x * qq.x + w4.y * qq.y + w4.z * qq.z + w4.w * qq.w;
            }
            xy_s[t] = offB[s * 72 + t] + a0;
        }
        __syncthreads();
        if (t < NPTS) {
            float px = xy_s[2 * t + 0] + rpx;
            float py = xy_s[2 * t + 1] + rpy;
            float x = fminf(fmaxf(px * (float)WID - 0.5f, 0.f), (float)(WID - 1));
            float y = fminf(fmaxf(py * (float)HGT - 0.5f, 0.f), (float)(HGT - 1));
            float x0f = floorf(x), y0f = floorf(y);
            float wx = x - x0f, wy = y - y0f;
            int x0 = (int)x0f, y0 = (int)y0f;
            int x1 = min(x0 + 1, WID - 1), y1 = min(y0 + 1, HGT - 1);
            const float inv = 1.f / (float)NPTS;
            w_s[4 * t + 0] = (1.f - wx) * (1.f - wy) * inv;
            w_s[4 * t + 1] = wx * (1.f - wy) * inv;
            w_s[4 * t + 2] = (1.f - wx) * wy * inv;
            w_s[4 * t + 3] = wx * wy * inv;
            off_s[4 * t + 0] = y0 * WID + x0;
            off_s[4 * t + 1] = y0 * WID + x1;
            off_s[4 * t + 2] = y1 * WID + x0;
            off_s[4 * t + 3] = y1 * WID + x1;
        }
        __syncthreads();
        {
            float acc = 0.f;
            const float* basef = fm  + ((size_t)b * HIDN + t) * HW;
            const float* basep = pos + ((size_t)b * HIDN + t) * HW;
            #pragma unroll 6
            for (int p = 0; p < NPTS; ++p)
                for (int k = 0; k < 4; ++k) {
                    int idx = off_s[4 * p + k];
                    acc += w_s[4 * p + k] * (basef[idx] + basep[idx]);
                }
            fused_s[t] = acc;
        }
        __syncthreads();
        {
            const float4* w1 = (const float4*)(uW1 + ((size_t)s * HIDN + t) * (2 * HIDN));
            const float4* f4 = (const float4*)fused_s;
            const float4* q4 = (const float4*)q_s;
            float a0 = 0.f;
            #pragma unroll 8
            for (int k = 0; k < HIDN / 4; ++k) {
                float4 w4 = w1[k]; float4 c4 = f4[k];
                a0 += w4.x * c4.x + w4.y * c4.y + w4.z * c4.z + w4.w * c4.w;
            }
            #pragma unroll 8
            for (int k = 0; k < HIDN / 4; ++k) {
                float4 w4 = w1[HIDN / 4 + k]; float4 c4 = q4[k];
                a0 += w4.x * c4.x + w4.y * c4.y + w4.z * c4.z + w4.w * c4.w;
            }
            hdd_s[t] = fmaxf(uB1[s * HIDN + t] + a0, 0.f);
        }
        __syncthreads();
        {
            const float4* w2 = (const float4*)(uW2 + ((size_t)s * HIDN + t) * HIDN);
            const float4* h4 = (const float4*)hdd_s;
            float a0 = 0.f;
            #pragma unroll 8
            for (int k = 0; k < HIDN / 4; ++k) {
                float4 w4 = w2[k]; float4 c4 = h4[k];
                a0 += w4.x * c4.x + w4.y * c4.y + w4.z * c4.z + w4.w * c4.w;
            }
            q_s[t] = uB2[s * HIDN + t] + a0;
        }
    }
    __syncthreads();
    {
        const float4* w = (const float4*)(bW1 + (size_t)t * HIDN);
        const float4* q4 = (const float4*)q_s;
        float a0 = 0.f;
        #pragma unroll 8
        for (int k = 0; k < HIDN / 4; ++k) {
            float4 w4 = w[k]; float4 c4 = q4[k];
            a0 += w4.x * c4.x + w4.y * c4.y + w4.z * c4.z + w4.w * c4.w;
        }
        hdd_s[t] = fmaxf(bb1[t] + a0, 0.f);
    }
    __syncthreads();
    {
        const float4* w = (const float4*)(bW2 + (size_t)t * HIDN);
        const float4* h4 = (const float4*)hdd_s;
        float a0 = 0.f;
        #pragma unroll 8
        for (int k = 0; k < HIDN / 4; ++k) {
            float4 w4 = w[k]; float4 c4 = h4[k];
            a0 += w4.x * c4.x + w4.y * c4.y + w4.z * c4.z + w4.w * c4.w;
        }
        fused_s[t] = fmaxf(bb2[t] + a0, 0.f);
    }
    __syncthreads();
    if (t < 4) {
        const float* w = bW3 + (size_t)t * HIDN;
        float h = bb3[t];
        #pragma unroll 16
        for (int k = 0; k < HIDN; ++k) h += w[k] * fused_s[k];
        out[(size_t)b * 4 + t] = 1.f / (1.f + expf(-h));
    }
}

// ---------------------------------------------------------------------------
extern "C" void kernel_launch(void* const* d_in, const int* in_sizes, int n_in,
                              void* d_out, int out_size, void* d_ws, size_t ws_size,
                              hipStream_t stream)
{
    const float* q    = (const float*)d_in[0];
    const float* rp   = (const float*)d_in[1];
    const float* fm   = (const float*)d_in[2];
    const float* pos  = (const float*)d_in[3];
    const float* offW = (const float*)d_in[4];
    const float* offB = (const float*)d_in[5];
    const float* uW1  = (const float*)d_in[6];
    const float* uB1  = (const float*)d_in[7];
    const float* uW2  = (const float*)d_in[8];
    const float* uB2  = (const float*)d_in[9];
    const float* bW1  = (const float*)d_in[10];
    const float* bb1  = (const float*)d_in[11];
    const float* bW2  = (const float*)d_in[12];
    const float* bb2  = (const float*)d_in[13];
    const float* bW3  = (const float*)d_in[14];
    const float* bb3  = (const float*)d_in[15];
    float* out = (float*)d_out;

    const size_t need = (size_t)B_SZ * HW * HIDN * sizeof(unsigned short);
    if (ws_size >= need) {
        unsigned short* fmp = (unsigned short*)d_ws;
        prepass_kernel<<<dim3(HIDN / 64, B_SZ), 512, 0, stream>>>(fm, pos, fmp);
        mdetr5_kernel<<<B_SZ / MB, NTHR, 0, stream>>>(
            q, rp, fmp, offW, offB, uW1, uB1, uW2, uB2,
            bW1, bb1, bW2, bb2, bW3, bb3, out);
    } else {
        mdetr_direct_kernel<<<B_SZ, 256, 0, stream>>>(
            q, rp, fm, pos, offW, offB, uW1, uB1, uW2, uB2,
            bW1, bb1, bW2, bb2, bW3, bb3, out);
    }
}

// Round 9
// 349.774 us; speedup vs baseline: 1.0076x; 1.0076x over previous
//
#include <hip/hip_runtime.h>
#include <hip/hip_bf16.h>

#define B_SZ   1024
#define HIDN   256
#define NSTAGE 6
#define NPTS   36
#define HGT    20
#define WID    20
#define HW     400
#define MB     4
#define NTHR   1024

// weight segment offsets (elements) inside the packed bf16 weight block
#define W_OFFW   0
#define W_UW1    110592                 // 6*72*256
#define W_UW2    897024                 // + 6*256*512
#define W_BW1    1290240                // + 6*256*256
#define W_BW2    1355776                // + 256*256
#define W_TOTAL  1421312                // + 256*256

// f32 -> bf16 round-to-nearest-even
static __device__ __forceinline__ unsigned int f2bf(float x) {
    unsigned int u = __float_as_uint(x);
    u += 0x7FFFu + ((u >> 16) & 1u);
    return u >> 16;
}
// bf16 bits -> f32 (exact)
static __device__ __forceinline__ float bf2f(unsigned short h) {
    return __uint_as_float((unsigned int)h << 16);
}
static __device__ __forceinline__ float bflo(unsigned int u) {
    return __uint_as_float(u << 16);
}
static __device__ __forceinline__ float bfhi(unsigned int u) {
    return __uint_as_float(u & 0xFFFF0000u);
}

// ---------------------------------------------------------------------------
// Weight repack: concatenated bf16 copies of offW|uW1|uW2|bW1|bW2 into ws.
// ---------------------------------------------------------------------------
__global__ __launch_bounds__(256) void wconv_kernel(
    const float* __restrict__ offW, const float* __restrict__ uW1,
    const float* __restrict__ uW2,  const float* __restrict__ bW1,
    const float* __restrict__ bW2,  unsigned short* __restrict__ dst)
{
    int i = blockIdx.x * 256 + threadIdx.x;
    if (i >= W_TOTAL) return;
    float v;
    if (i < W_UW1)       v = offW[i - W_OFFW];
    else if (i < W_UW2)  v = uW1[i - W_UW1];
    else if (i < W_BW1)  v = uW2[i - W_UW2];
    else if (i < W_BW2)  v = bW1[i - W_BW1];
    else                 v = bW2[i - W_BW2];
    dst[i] = (unsigned short)f2bf(v);
}

// ---------------------------------------------------------------------------
// Prepass v8: fmp layout [b][ct][hw][cw]  (ct = c/64, cw = c%64).
// 640 threads -> exactly 10 read iterations; loads issued in PAIRS (4x float4
// in flight per wave before the dependent LDS writes) to double per-wave MLP.
// Reads: two contiguous 102.4 KB streams. Write: one contiguous 51.2 KB
// stream. LDS tile[hw][c] ushort stride 65 (odd) - conflict-benign.
// ---------------------------------------------------------------------------
__global__ __launch_bounds__(640) void prepass_kernel(
    const float* __restrict__ fm, const float* __restrict__ pos,
    unsigned short* __restrict__ fmp)
{
    const int b  = blockIdx.y;
    const int ct = blockIdx.x;                    // 0..3
    __shared__ unsigned short tile[HW * 65];      // 52,000 B
    const int t = threadIdx.x;

    const size_t gbase = ((size_t)b * HIDN + ct * 64) * HW;
    #pragma unroll 1
    for (int k = 0; k < 5; ++k) {
        const int i0 = t + (2 * k) * 640;
        const int i1 = i0 + 640;
        const float4 a0 = *(const float4*)(fm  + gbase + 4 * (size_t)i0);
        const float4 q0 = *(const float4*)(pos + gbase + 4 * (size_t)i0);
        const float4 a1 = *(const float4*)(fm  + gbase + 4 * (size_t)i1);
        const float4 q1 = *(const float4*)(pos + gbase + 4 * (size_t)i1);
        const int c0 = i0 / 100, k40 = i0 - c0 * 100;
        const int c1 = i1 / 100, k41 = i1 - c1 * 100;
        tile[(4 * k40 + 0) * 65 + c0] = (unsigned short)f2bf(a0.x + q0.x);
        tile[(4 * k40 + 1) * 65 + c0] = (unsigned short)f2bf(a0.y + q0.y);
        tile[(4 * k40 + 2) * 65 + c0] = (unsigned short)f2bf(a0.z + q0.z);
        tile[(4 * k40 + 3) * 65 + c0] = (unsigned short)f2bf(a0.w + q0.w);
        tile[(4 * k41 + 0) * 65 + c1] = (unsigned short)f2bf(a1.x + q1.x);
        tile[(4 * k41 + 1) * 65 + c1] = (unsigned short)f2bf(a1.y + q1.y);
        tile[(4 * k41 + 2) * 65 + c1] = (unsigned short)f2bf(a1.z + q1.z);
        tile[(4 * k41 + 3) * 65 + c1] = (unsigned short)f2bf(a1.w + q1.w);
    }
    __syncthreads();

    // ---- contiguous write: 400 rows x 128 B sequential ----
    const int u2 = t & 31;                        // channel pair 0..31
    const int h0 = t >> 5;                        // 0..19
    uint* outp = (uint*)(fmp + (((size_t)b * 4 + ct) * HW) * 64);
    #pragma unroll
    for (int w = 0; w < 20; ++w) {
        const int hw = h0 + 20 * w;
        const unsigned int lo = tile[hw * 65 + 2 * u2 + 0];
        const unsigned int hi = tile[hw * 65 + 2 * u2 + 1];
        outp[(size_t)hw * 32 + u2] = lo | (hi << 16);
    }
}

// ---------------------------------------------------------------------------
// f32-weight GEMM (kept for bW3 / fallback-free epilogue). kp-split, MB=4.
// ---------------------------------------------------------------------------
template <int K, int O, int ACT>
__device__ __forceinline__ void gemm_v3(
    const float* __restrict__ W, const float* __restrict__ bias,
    const float* __restrict__ i0, const float* __restrict__ i1,
    const float* __restrict__ i2, const float* __restrict__ i3,
    float* __restrict__ o0, float* __restrict__ o1,
    float* __restrict__ o2, float* __restrict__ o3,
    int kp, int og)
{
    const float4* p0 = (const float4*)i0;
    const float4* p1 = (const float4*)i1;
    const float4* p2 = (const float4*)i2;
    const float4* p3 = (const float4*)i3;
    #pragma unroll
    for (int pass = 0; pass < (O + 127) / 128; ++pass) {
        const int o = pass * 128 + og;
        float a0 = 0.f, a1 = 0.f, a2 = 0.f, a3 = 0.f;
        if (o < O) {
            const float4* wr = (const float4*)(W + (size_t)o * K);
            #pragma unroll 4
            for (int jj = 0; jj < K / 32; ++jj) {
                const int j = kp + 8 * jj;
                const float4 w  = wr[j];
                const float4 v0 = p0[j];
                const float4 v1 = p1[j];
                const float4 v2 = p2[j];
                const float4 v3 = p3[j];
                a0 += w.x * v0.x + w.y * v0.y + w.z * v0.z + w.w * v0.w;
                a1 += w.x * v1.x + w.y * v1.y + w.z * v1.z + w.w * v1.w;
                a2 += w.x * v2.x + w.y * v2.y + w.z * v2.z + w.w * v2.w;
                a3 += w.x * v3.x + w.y * v3.y + w.z * v3.z + w.w * v3.w;
            }
        }
        a0 += __shfl_xor(a0, 1); a0 += __shfl_xor(a0, 2); a0 += __shfl_xor(a0, 4);
        a1 += __shfl_xor(a1, 1); a1 += __shfl_xor(a1, 2); a1 += __shfl_xor(a1, 4);
        a2 += __shfl_xor(a2, 1); a2 += __shfl_xor(a2, 2); a2 += __shfl_xor(a2, 4);
        a3 += __shfl_xor(a3, 1); a3 += __shfl_xor(a3, 2); a3 += __shfl_xor(a3, 4);
        if (kp == 0 && o < O) {
            const float bz = bias[o];
            float r0 = a0 + bz, r1 = a1 + bz, r2 = a2 + bz, r3 = a3 + bz;
            if (ACT == 1) {
                r0 = fmaxf(r0, 0.f); r1 = fmaxf(r1, 0.f);
                r2 = fmaxf(r2, 0.f); r3 = fmaxf(r3, 0.f);
            }
            if (ACT == 2) {
                r0 = 1.f / (1.f + expf(-r0)); r1 = 1.f / (1.f + expf(-r1));
                r2 = 1.f / (1.f + expf(-r2)); r3 = 1.f / (1.f + expf(-r3));
            }
            o0[o] = r0; o1[o] = r1; o2[o] = r2; o3[o] = r3;
        }
    }
}

// ---------------------------------------------------------------------------
// bf16-weight GEMM: uint2 = 4 bf16 weights per k-quad (half the weight bytes
// and half the weight-load instructions of gemm_v3). Inputs f32 from LDS,
// FMAs in f32. Same k-mapping as gemm_v3 (w0..w3 <-> v.x..v.w).
// ---------------------------------------------------------------------------
template <int K, int O, int ACT>
__device__ __forceinline__ void gemm_bf(
    const unsigned short* __restrict__ W, const float* __restrict__ bias,
    const float* __restrict__ i0, const float* __restrict__ i1,
    const float* __restrict__ i2, const float* __restrict__ i3,
    float* __restrict__ o0, float* __restrict__ o1,
    float* __restrict__ o2, float* __restrict__ o3,
    int kp, int og)
{
    const float4* p0 = (const float4*)i0;
    const float4* p1 = (const float4*)i1;
    const float4* p2 = (const float4*)i2;
    const float4* p3 = (const float4*)i3;
    #pragma unroll
    for (int pass = 0; pass < (O + 127) / 128; ++pass) {
        const int o = pass * 128 + og;
        float a0 = 0.f, a1 = 0.f, a2 = 0.f, a3 = 0.f;
        if (o < O) {
            const uint2* wr = (const uint2*)(W + (size_t)o * K);
            #pragma unroll 4
            for (int jj = 0; jj < K / 32; ++jj) {
                const int j = kp + 8 * jj;
                const uint2 wq = wr[j];
                const float w0 = bflo(wq.x), w1 = bfhi(wq.x);
                const float w2 = bflo(wq.y), w3 = bfhi(wq.y);
                const float4 v0 = p0[j];
                const float4 v1 = p1[j];
                const float4 v2 = p2[j];
                const float4 v3 = p3[j];
                a0 += w0 * v0.x + w1 * v0.y + w2 * v0.z + w3 * v0.w;
                a1 += w0 * v1.x + w1 * v1.y + w2 * v1.z + w3 * v1.w;
                a2 += w0 * v2.x + w1 * v2.y + w2 * v2.z + w3 * v2.w;
                a3 += w0 * v3.x + w1 * v3.y + w2 * v3.z + w3 * v3.w;
            }
        }
        a0 += __shfl_xor(a0, 1); a0 += __shfl_xor(a0, 2); a0 += __shfl_xor(a0, 4);
        a1 += __shfl_xor(a1, 1); a1 += __shfl_xor(a1, 2); a1 += __shfl_xor(a1, 4);
        a2 += __shfl_xor(a2, 1); a2 += __shfl_xor(a2, 2); a2 += __shfl_xor(a2, 4);
        a3 += __shfl_xor(a3, 1); a3 += __shfl_xor(a3, 2); a3 += __shfl_xor(a3, 4);
        if (kp == 0 && o < O) {
            const float bz = bias[o];
            float r0 = a0 + bz, r1 = a1 + bz, r2 = a2 + bz, r3 = a3 + bz;
            if (ACT == 1) {
                r0 = fmaxf(r0, 0.f); r1 = fmaxf(r1, 0.f);
                r2 = fmaxf(r2, 0.f); r3 = fmaxf(r3, 0.f);
            }
            if (ACT == 2) {
                r0 = 1.f / (1.f + expf(-r0)); r1 = 1.f / (1.f + expf(-r1));
                r2 = 1.f / (1.f + expf(-r2)); r3 = 1.f / (1.f + expf(-r3));
            }
            o0[o] = r0; o1[o] = r1; o2[o] = r2; o3[o] = r3;
        }
    }
}

// ---------------------------------------------------------------------------
// Fused main kernel v6: 1 block = 4 batch elements, 1024 threads, 256 blocks.
// bf16 fmp in [b][ct][hw][cw] layout; bf16 weights (uint2 loads).
// ---------------------------------------------------------------------------
__global__ __launch_bounds__(NTHR) void mdetr6_kernel(
    const float* __restrict__ q_in,  const float* __restrict__ refpt,
    const unsigned short* __restrict__ fmp,
    const unsigned short* __restrict__ offWb, const float* __restrict__ offB,
    const unsigned short* __restrict__ uW1b,  const float* __restrict__ uB1,
    const unsigned short* __restrict__ uW2b,  const float* __restrict__ uB2,
    const unsigned short* __restrict__ bW1b,  const float* __restrict__ bb1,
    const unsigned short* __restrict__ bW2b,  const float* __restrict__ bb2,
    const float* __restrict__ bW3,   const float* __restrict__ bb3,
    float* __restrict__ out)
{
    const int b0 = blockIdx.x * MB;
    const int t  = threadIdx.x;
    const int kp = t & 7;
    const int og = t >> 3;

    __shared__ __attribute__((aligned(16))) float cat_s[MB][2 * HIDN]; // [fused|q]
    __shared__ __attribute__((aligned(16))) float hdd_s[MB][HIDN];
    __shared__ __attribute__((aligned(16))) float xy_s[MB][80];
    __shared__ __attribute__((aligned(16))) float wgt_s[MB][144];
    __shared__ __attribute__((aligned(16))) int   off_s[MB][144];

    {   // initial q
        const int m = t >> 8, c = t & 255;
        cat_s[m][HIDN + c] = q_in[(size_t)(b0 + m) * HIDN + c];
    }

    for (int s = 0; s < NSTAGE; ++s) {
        __syncthreads();
        // ---- offset generator ----
        gemm_bf<HIDN, NPTS * 2, 0>(
            offWb + (size_t)s * NPTS * 2 * HIDN, offB + s * NPTS * 2,
            cat_s[0] + HIDN, cat_s[1] + HIDN, cat_s[2] + HIDN, cat_s[3] + HIDN,
            xy_s[0], xy_s[1], xy_s[2], xy_s[3], kp, og);
        __syncthreads();
        // ---- tap prep (offsets scaled for 64-channel sub-rows) ----
        if (t < MB * NPTS) {
            const int m = t / NPTS, p = t % NPTS;
            const int bm = b0 + m;
            float px = xy_s[m][2 * p + 0] + refpt[2 * bm + 0];
            float py = xy_s[m][2 * p + 1] + refpt[2 * bm + 1];
            float x = fminf(fmaxf(px * (float)WID - 0.5f, 0.f), (float)(WID - 1));
            float y = fminf(fmaxf(py * (float)HGT - 0.5f, 0.f), (float)(HGT - 1));
            float x0f = floorf(x), y0f = floorf(y);
            float wx = x - x0f,   wy = y - y0f;
            int x0 = (int)x0f, y0 = (int)y0f;
            int x1 = min(x0 + 1, WID - 1), y1 = min(y0 + 1, HGT - 1);
            const float inv = 1.f / (float)NPTS;
            wgt_s[m][4 * p + 0] = (1.f - wx) * (1.f - wy) * inv;
            wgt_s[m][4 * p + 1] = wx * (1.f - wy) * inv;
            wgt_s[m][4 * p + 2] = (1.f - wx) * wy * inv;
            wgt_s[m][4 * p + 3] = wx * wy * inv;
            off_s[m][4 * p + 0] = (y0 * WID + x0) * 64;
            off_s[m][4 * p + 1] = (y0 * WID + x1) * 64;
            off_s[m][4 * p + 2] = (y1 * WID + x0) * 64;
            off_s[m][4 * p + 3] = (y1 * WID + x1) * 64;
        }
        __syncthreads();
        // ---- gather + pooled mean -> fused ----
        {
            const int m = t >> 8, c = t & 255;
            const unsigned short* base =
                fmp + (((size_t)(b0 + m) * 4 + (c >> 6)) * HW) * 64 + (c & 63);
            float acc = 0.f;
            #pragma unroll 6
            for (int p = 0; p < NPTS; ++p) {
                const int4   o4 = ((const int4*)off_s[m])[p];
                const float4 w4 = ((const float4*)wgt_s[m])[p];
                acc += w4.x * bf2f(base[o4.x]) + w4.y * bf2f(base[o4.y])
                     + w4.z * bf2f(base[o4.z]) + w4.w * bf2f(base[o4.w]);
            }
            cat_s[m][c] = acc;
        }
        __syncthreads();
        // ---- MLP1 ----
        gemm_bf<2 * HIDN, HIDN, 1>(
            uW1b + (size_t)s * HIDN * 2 * HIDN, uB1 + s * HIDN,
            cat_s[0], cat_s[1], cat_s[2], cat_s[3],
            hdd_s[0], hdd_s[1], hdd_s[2], hdd_s[3], kp, og);
        __syncthreads();
        // ---- MLP2 ----
        gemm_bf<HIDN, HIDN, 0>(
            uW2b + (size_t)s * HIDN * HIDN, uB2 + s * HIDN,
            hdd_s[0], hdd_s[1], hdd_s[2], hdd_s[3],
            cat_s[0] + HIDN, cat_s[1] + HIDN, cat_s[2] + HIDN, cat_s[3] + HIDN,
            kp, og);
    }
    __syncthreads();
    // ---- bbox head ----
    gemm_bf<HIDN, HIDN, 1>(bW1b, bb1,
        cat_s[0] + HIDN, cat_s[1] + HIDN, cat_s[2] + HIDN, cat_s[3] + HIDN,
        hdd_s[0], hdd_s[1], hdd_s[2], hdd_s[3], kp, og);
    __syncthreads();
    gemm_bf<HIDN, HIDN, 1>(bW2b, bb2,
        hdd_s[0], hdd_s[1], hdd_s[2], hdd_s[3],
        cat_s[0], cat_s[1], cat_s[2], cat_s[3], kp, og);
    __syncthreads();
    gemm_v3<HIDN, 4, 2>(bW3, bb3,
        cat_s[0], cat_s[1], cat_s[2], cat_s[3],
        out + (size_t)(b0 + 0) * 4, out + (size_t)(b0 + 1) * 4,
        out + (size_t)(b0 + 2) * 4, out + (size_t)(b0 + 3) * 4, kp, og);
}

// ---------------------------------------------------------------------------
// Fallback (no workspace): 1 block = 1 batch element, direct strided gather.
// ---------------------------------------------------------------------------
__global__ __launch_bounds__(256) void mdetr_direct_kernel(
    const float* __restrict__ q_in,  const float* __restrict__ refpt,
    const float* __restrict__ fm,    const float* __restrict__ pos,
    const float* __restrict__ offW,  const float* __restrict__ offB,
    const float* __restrict__ uW1,   const float* __restrict__ uB1,
    const float* __restrict__ uW2,   const float* __restrict__ uB2,
    const float* __restrict__ bW1,   const float* __restrict__ bb1,
    const float* __restrict__ bW2,   const float* __restrict__ bb2,
    const float* __restrict__ bW3,   const float* __restrict__ bb3,
    float* __restrict__ out)
{
    const int b = blockIdx.x;
    const int t = threadIdx.x;
    __shared__ __attribute__((aligned(16))) float q_s[HIDN];
    __shared__ __attribute__((aligned(16))) float fused_s[HIDN];
    __shared__ __attribute__((aligned(16))) float hdd_s[HIDN];
    __shared__ float xy_s[NPTS * 2];
    __shared__ int   off_s[NPTS * 4];
    __shared__ float w_s[NPTS * 4];

    q_s[t] = q_in[(size_t)b * HIDN + t];
    const float rpx = refpt[2 * b + 0];
    const float rpy = refpt[2 * b + 1];

    for (int s = 0; s < NSTAGE; ++s) {
        __syncthreads();
        if (t < NPTS * 2) {
            const float4* wrow = (const float4*)(offW + ((size_t)s * 72 + t) * HIDN);
            const float4* q4   = (const float4*)q_s;
            float a0 = 0.f;
            #pragma unroll 8
            for (int k = 0; k < HIDN / 4; ++k) {
                float4 w4 = wrow[k]; float4 qq = q4[k];
                a0 += w4.x * qq.x + w4.y * qq.y + w4.z * qq.z + w4.w * qq.w;
            }
            xy_s[t] = offB[s * 72 + t] + a0;
        }
        __syncthreads();
        if (t < NPTS) {
            float px = xy_s[2 * t + 0] + rpx;
            float py = xy_s[2 * t + 1] + rpy;
            float x = fminf(fmaxf(px * (float)WID - 0.5f, 0.f), (float)(WID - 1));
            float y = fminf(fmaxf(py * (float)HGT - 0.5f, 0.f), (float)(HGT - 1));
            float x0f = floorf(x), y0f = floorf(y);
            float wx = x - x0f, wy = y - y0f;
            int x0 = (int)x0f, y0 = (int)y0f;
            int x1 = min(x0 + 1, WID - 1), y1 = min(y0 + 1, HGT - 1);
            const float inv = 1.f / (float)NPTS;
            w_s[4 * t + 0] = (1.f - wx) * (1.f - wy) * inv;
            w_s[4 * t + 1] = wx * (1.f - wy) * inv;
            w_s[4 * t + 2] = (1.f - wx) * wy * inv;
            w_s[4 * t + 3] = wx * wy * inv;
            off_s[4 * t + 0] = y0 * WID + x0;
            off_s[4 * t + 1] = y0 * WID + x1;
            off_s[4 * t + 2] = y1 * WID + x0;
            off_s[4 * t + 3] = y1 * WID + x1;
        }
        __syncthreads();
        {
            float acc = 0.f;
            const float* basef = fm  + ((size_t)b * HIDN + t) * HW;
            const float* basep = pos + ((size_t)b * HIDN + t) * HW;
            #pragma unroll 6
            for (int p = 0; p < NPTS; ++p)
                for (int k = 0; k < 4; ++k) {
                    int idx = off_s[4 * p + k];
                    acc += w_s[4 * p + k] * (basef[idx] + basep[idx]);
                }
            fused_s[t] = acc;
        }
        __syncthreads();
        {
            const float4* w1 = (const float4*)(uW1 + ((size_t)s * HIDN + t) * (2 * HIDN));
            const float4* f4 = (const float4*)fused_s;
            const float4* q4 = (const float4*)q_s;
            float a0 = 0.f;
            #pragma unroll 8
            for (int k = 0; k < HIDN / 4; ++k) {
                float4 w4 = w1[k]; float4 c4 = f4[k];
                a0 += w4.x * c4.x + w4.y * c4.y + w4.z * c4.z + w4.w * c4.w;
            }
            #pragma unroll 8
            for (int k = 0; k < HIDN / 4; ++k) {
                float4 w4 = w1[HIDN / 4 + k]; float4 c4 = q4[k];
                a0 += w4.x * c4.x + w4.y * c4.y + w4.z * c4.z + w4.w * c4.w;
            }
            hdd_s[t] = fmaxf(uB1[s * HIDN + t] + a0, 0.f);
        }
        __syncthreads();
        {
            const float4* w2 = (const float4*)(uW2 + ((size_t)s * HIDN + t) * HIDN);
            const float4* h4 = (const float4*)hdd_s;
            float a0 = 0.f;
            #pragma unroll 8
            for (int k = 0; k < HIDN / 4; ++k) {
                float4 w4 = w2[k]; float4 c4 = h4[k];
                a0 += w4.x * c4.x + w4.y * c4.y + w4.z * c4.z + w4.w * c4.w;
            }
            q_s[t] = uB2[s * HIDN + t] + a0;
        }
    }
    __syncthreads();
    {
        const float4* w = (const float4*)(bW1 + (size_t)t * HIDN);
        const float4* q4 = (const float4*)q_s;
        float a0 = 0.f;
        #pragma unroll 8
        for (int k = 0; k < HIDN / 4; ++k) {
            float4 w4 = w[k]; float4 c4 = q4[k];
            a0 += w4.x * c4.x + w4.y * c4.y + w4.z * c4.z + w4.w * c4.w;
        }
        hdd_s[t] = fmaxf(bb1[t] + a0, 0.f);
    }
    __syncthreads();
    {
        const float4* w = (const float4*)(bW2 + (size_t)t * HIDN);
        const float4* h4 = (const float4*)hdd_s;
        float a0 = 0.f;
        #pragma unroll 8
        for (int k = 0; k < HIDN / 4; ++k) {
            float4 w4 = w[k]; float4 c4 = h4[k];
            a0 += w4.x * c4.x + w4.y * c4.y + w4.z * c4.z + w4.w * c4.w;
        }
        fused_s[t] = fmaxf(bb2[t] + a0, 0.f);
    }
    __syncthreads();
    if (t < 4) {
        const float* w = bW3 + (size_t)t * HIDN;
        float h = bb3[t];
        #pragma unroll 16
        for (int k = 0; k < HIDN; ++k) h += w[k] * fused_s[k];
        out[(size_t)b * 4 + t] = 1.f / (1.f + expf(-h));
    }
}

// ---------------------------------------------------------------------------
extern "C" void kernel_launch(void* const* d_in, const int* in_sizes, int n_in,
                              void* d_out, int out_size, void* d_ws, size_t ws_size,
                              hipStream_t stream)
{
    const float* q    = (const float*)d_in[0];
    const float* rp   = (const float*)d_in[1];
    const float* fm   = (const float*)d_in[2];
    const float* pos  = (const float*)d_in[3];
    const float* offW = (const float*)d_in[4];
    const float* offB = (const float*)d_in[5];
    const float* uW1  = (const float*)d_in[6];
    const float* uB1  = (const float*)d_in[7];
    const float* uW2  = (const float*)d_in[8];
    const float* uB2  = (const float*)d_in[9];
    const float* bW1  = (const float*)d_in[10];
    const float* bb1  = (const float*)d_in[11];
    const float* bW2  = (const float*)d_in[12];
    const float* bb2  = (const float*)d_in[13];
    const float* bW3  = (const float*)d_in[14];
    const float* bb3  = (const float*)d_in[15];
    float* out = (float*)d_out;

    const size_t fmp_elems = (size_t)B_SZ * HW * HIDN;          // 104,857,600
    const size_t need = (fmp_elems + W_TOTAL) * sizeof(unsigned short);
    if (ws_size >= need) {
        unsigned short* fmp = (unsigned short*)d_ws;
        unsigned short* wbf = fmp + fmp_elems;
        wconv_kernel<<<W_TOTAL / 256, 256, 0, stream>>>(offW, uW1, uW2, bW1, bW2, wbf);
        prepass_kernel<<<dim3(4, B_SZ), 640, 0, stream>>>(fm, pos, fmp);
        mdetr6_kernel<<<B_SZ / MB, NTHR, 0, stream>>>(
            q, rp, fmp,
            wbf + W_OFFW, offB, wbf + W_UW1, uB1, wbf + W_UW2, uB2,
            wbf + W_BW1, bb1, wbf + W_BW2, bb2, bW3, bb3, out);
    } else {
        mdetr_direct_kernel<<<B_SZ, 256, 0, stream>>>(
            q, rp, fm, pos, offW, offB, uW1, uB1, uW2, uB2,
            bW1, bb1, bW2, bb2, bW3, bb3, out);
    }
}